// Round 1
// baseline (706.630 us; speedup 1.0000x reference)
//
#include <hip/hip_runtime.h>
#include <hip/hip_bf16.h>

// Problem: GraphAttentionLayer. B=4, N=4096, F_in=128, F_out=64.
// Key reduction: attention = where(adj>0, softmax_e, -9e15); out = sigmoid(att @ hW).
// z = S_soft + (-9e15)*S_mask where S_mask = sum_{adj==0} hW[b,j,o].
// |S_soft| <= ~60, |9e15*S_mask| >= ~5e12 for all entries => sigmoid saturates:
// out = (S_mask < 0) ? 1.0f : 0.0f. Compute S_mask (and hW) in f64 for
// sign-exactness vs the f64 numpy reference.

#define GN 4096
#define GB 4
#define FIN 128
#define FOUT 64
#define BI 16
#define BJ 32

// ---- kernel 1: pack (adj == 0) into bitmask, 128 uint32 words per row ----
__global__ __launch_bounds__(256) void pack_kernel(const int* __restrict__ adj,
                                                   unsigned int* __restrict__ mbits) {
    int wavesPerBlock = blockDim.x >> 6;
    int gid = blockIdx.x * wavesPerBlock + (threadIdx.x >> 6);  // global wave id
    int lane = threadIdx.x & 63;
    // total waves = GN * (GN/64) = 4096 * 64
    int i = gid >> 6;       // row
    int w = gid & 63;       // 64-j group
    int j = w * 64 + lane;
    unsigned long long m = __ballot(adj[(size_t)i * GN + j] == 0);
    if (lane == 0) {
        mbits[(size_t)i * (GN / 32) + (size_t)w * 2]     = (unsigned int)m;
        mbits[(size_t)i * (GN / 32) + (size_t)w * 2 + 1] = (unsigned int)(m >> 32);
    }
}

// ---- kernel 2: hW = h @ W in f64 ----
__global__ __launch_bounds__(64) void hw_kernel(const float* __restrict__ h,
                                                const float* __restrict__ W,
                                                double* __restrict__ hW) {
    int bn = blockIdx.x;          // 0 .. B*N-1
    int o = threadIdx.x;          // 0..63
    __shared__ float hs[FIN];
    hs[o]      = h[(size_t)bn * FIN + o];
    hs[o + 64] = h[(size_t)bn * FIN + o + 64];
    __syncthreads();
    double acc = 0.0;
#pragma unroll
    for (int i = 0; i < FIN; ++i)
        acc = fma((double)hs[i], (double)W[i * FOUT + o], acc);
    hW[(size_t)bn * FOUT + o] = acc;
}

// ---- kernel 3: S_mask = (adj==0) @ hW ; out = sign test ----
__global__ __launch_bounds__(256) void smask_kernel(const double* __restrict__ hW,
                                                    const unsigned int* __restrict__ mbits,
                                                    float* __restrict__ out) {
    const int i0 = blockIdx.x * BI;
    const int t = threadIdx.x;            // 0..255
    const int b = t >> 6, o = t & 63;

    __shared__ double hwt[BJ][256];

    double acc[BI];
#pragma unroll
    for (int ii = 0; ii < BI; ++ii) acc[ii] = 0.0;

    const double* hwp = hW + (size_t)b * GN * FOUT + o;   // + j*FOUT

    for (int j0 = 0; j0 < GN; j0 += BJ) {
        // stage hW tile [BJ][256] (per-wave contiguous 512B loads)
#pragma unroll
        for (int jj = 0; jj < BJ; ++jj)
            hwt[jj][t] = hwp[(size_t)(j0 + jj) * FOUT];
        __syncthreads();

        // mask words for the BI rows at this j-tile (uniform -> scalar loads)
        const int w = j0 >> 5;
        unsigned int mrow[BI];
#pragma unroll
        for (int ii = 0; ii < BI; ++ii)
            mrow[ii] = mbits[(size_t)(i0 + ii) * (GN / 32) + w];

#pragma unroll
        for (int jj = 0; jj < BJ; ++jj) {
            double v = hwt[jj][t];
#pragma unroll
            for (int ii = 0; ii < BI; ++ii) {
                double m = (double)((mrow[ii] >> jj) & 1u);
                acc[ii] = fma(m, v, acc[ii]);
            }
        }
        __syncthreads();
    }

#pragma unroll
    for (int ii = 0; ii < BI; ++ii) {
        float r = acc[ii] < 0.0 ? 1.0f : (acc[ii] > 0.0 ? 0.0f : 0.5f);
        out[((size_t)b * GN + (i0 + ii)) * FOUT + o] = r;
    }
}

extern "C" void kernel_launch(void* const* d_in, const int* in_sizes, int n_in,
                              void* d_out, int out_size, void* d_ws, size_t ws_size,
                              hipStream_t stream) {
    const float* h   = (const float*)d_in[0];   // [4,4096,128]
    const int*   adj = (const int*)d_in[1];     // [4096,4096]
    const float* W   = (const float*)d_in[2];   // [128,64]
    // d_in[3] = a : numerically irrelevant (see analysis)
    float* out = (float*)d_out;                 // [4,4096,64]

    // workspace layout: hW f64 (8 MB) | mbits (2 MB)
    double* hW = (double*)d_ws;
    unsigned int* mbits = (unsigned int*)((char*)d_ws + (size_t)GB * GN * FOUT * sizeof(double));

    // pack adj==0 bits: 4096*64 waves, 4 waves/block
    pack_kernel<<<(GN * (GN / 64)) / 4, 256, 0, stream>>>(adj, mbits);
    // hW in f64
    hw_kernel<<<GB * GN, 64, 0, stream>>>(h, W, hW);
    // masked sum + sign
    smask_kernel<<<GN / BI, 256, 0, stream>>>(hW, mbits, out);
}

// Round 2
// 126.471 us; speedup vs baseline: 5.5873x; 5.5873x over previous
//
#include <hip/hip_runtime.h>
#include <hip/hip_bf16.h>

// GraphAttentionLayer: out = sigmoid(S_soft - 9e15*S_mask) saturates =>
// out[b,i,o] = (S_mask[b,i,o] < 0) ? 1 : 0, S_mask = sum_{adj[i,j]==0} hW[b,j,o].
// Exact integer MFMA path:
//   q = rint(hW * 2^16)  (row quantization error <= 4096*2^-17 = 0.03125)
//   q = d0 + 256*d1 + 65536*d2, balanced digits in [-128,127], exact in bf16.
//   mask bit (0/1) exact in bf16; all f32 MFMA partials are ints < 2^24 => EXACT.
//   S = c0 + 256*c1 + 65536*c2 (f64, exact). |S| > 2048 => sign reliable.
//   else: flagged output recomputed exactly in f64 by fixup kernel.

#define GN 4096
#define GB 4
#define FIN 128
#define FOUT 64
#define FLAG_CAP 262144

typedef short short8 __attribute__((ext_vector_type(8)));
typedef float f32x4 __attribute__((ext_vector_type(4)));
typedef unsigned int uint32x4 __attribute__((ext_vector_type(4)));

// ---- kernel 1: pack (adj == 0) into bitmask, 128 uint32 words per row ----
__global__ __launch_bounds__(256) void pack_kernel(const int* __restrict__ adj,
                                                   unsigned int* __restrict__ mbits) {
    int gid = blockIdx.x * 4 + (threadIdx.x >> 6);
    int lane = threadIdx.x & 63;
    int i = gid >> 6;       // row
    int w = gid & 63;       // 64-j group
    int j = w * 64 + lane;
    unsigned long long m = __ballot(adj[(size_t)i * GN + j] == 0);
    if (lane == 0) {
        mbits[(size_t)i * (GN / 32) + (size_t)w * 2]     = (unsigned int)m;
        mbits[(size_t)i * (GN / 32) + (size_t)w * 2 + 1] = (unsigned int)(m >> 32);
    }
}

// ---- kernel 2: hW = h @ W in f64, plus bf16 digit planes packed for MFMA B-frags ----
// Bp layout: [b][pair(64)][ (par*12 + cg*3 + l)*1024 + lane*16 + jj*2 ]
//   with j = pair*64 + par*32 + (lane>>4)*8 + jj, o = cg*16 + (lane&15)
__global__ __launch_bounds__(64) void hw_kernel(const float* __restrict__ h,
                                                const float* __restrict__ W,
                                                double* __restrict__ hW,
                                                unsigned short* __restrict__ Bp) {
    int bn = blockIdx.x;          // b*4096 + j
    int o = threadIdx.x;          // 0..63
    __shared__ float hs[FIN];
    hs[o]      = h[(size_t)bn * FIN + o];
    hs[o + 64] = h[(size_t)bn * FIN + o + 64];
    __syncthreads();
    double acc = 0.0;
#pragma unroll
    for (int i = 0; i < FIN; ++i)
        acc = fma((double)hs[i], (double)W[i * FOUT + o], acc);
    hW[(size_t)bn * FOUT + o] = acc;

    long long q = llrint(acc * 65536.0);
    int d0 = (int)(((q + 128) & 255) - 128); q = (q - d0) >> 8;
    int d1 = (int)(((q + 128) & 255) - 128); q = (q - d1) >> 8;
    int d2 = (int)q;  // |d2| <= ~64 given |hW| < 128

    int b = bn >> 12, j = bn & 4095;
    int lane16 = ((j >> 3) & 3) * 16 + (o & 15);
    size_t base = (size_t)b * (64 * 24576) + (size_t)(j >> 6) * 24576
                + (size_t)((((j >> 5) & 1) * 12 + (o >> 4) * 3) * 1024)
                + (size_t)lane16 * 16 + (size_t)(j & 7) * 2;
    int dg[3] = {d0, d1, d2};
#pragma unroll
    for (int l = 0; l < 3; ++l) {
        float f = (float)dg[l];                       // exact
        unsigned int u = __builtin_bit_cast(unsigned int, f);
        Bp[(base + (size_t)l * 1024) >> 1] = (unsigned short)(u >> 16);  // exact bf16
    }
}

// ---- kernel 3: exact bf16-MFMA masked-sum GEMM + sign epilogue ----
__global__ __launch_bounds__(512) void gemm_kernel(const unsigned char* __restrict__ Bp,
                                                   const unsigned int* __restrict__ mbits,
                                                   float* __restrict__ out,
                                                   unsigned int* __restrict__ flags,
                                                   unsigned int* __restrict__ counter) {
    __shared__ __align__(16) unsigned char lds[2 * 24576 + 64 * 129 * 4];
    unsigned int* maskw = (unsigned int*)(lds + 2 * 24576);

    const int tid = threadIdx.x;
    const int lane = tid & 63;
    const int wv = tid >> 6;
    const int cg = wv & 3;        // col group: o = cg*16 + (lane&15)
    const int kg = wv >> 2;       // K-parity group
    const int mt = (int)blockIdx.x >> 2;
    const int b = (int)blockIdx.x & 3;
    const int i0 = mt * 64;

    // stage mask rows (64 rows x 128 words) into LDS, stride 129 (conflict-free)
    {
        const int row = tid >> 3;
        const int c0 = (tid & 7) * 16;
        const unsigned int* src = mbits + (size_t)(i0 + row) * 128 + c0;
        unsigned int* dst = maskw + row * 129 + c0;
#pragma unroll
        for (int c = 0; c < 16; ++c) dst[c] = src[c];
    }

    const unsigned char* bpb = Bp + (size_t)b * (64 * 24576);
    const int soff = wv * 1024 + lane * 16;   // this thread's stage slot

    // prologue: stage pair 0 into buf0
    {
        uint32x4 st0 = *(const uint32x4*)(bpb + 0 * 8192 + soff);
        uint32x4 st1 = *(const uint32x4*)(bpb + 1 * 8192 + soff);
        uint32x4 st2 = *(const uint32x4*)(bpb + 2 * 8192 + soff);
        *(uint32x4*)(lds + 0 * 8192 + soff) = st0;
        *(uint32x4*)(lds + 1 * 8192 + soff) = st1;
        *(uint32x4*)(lds + 2 * 8192 + soff) = st2;
    }
    __syncthreads();

    f32x4 acc[4][3];
#pragma unroll
    for (int r = 0; r < 4; ++r)
#pragma unroll
        for (int l = 0; l < 3; ++l) {
            f32x4 z = {0.f, 0.f, 0.f, 0.f};
            acc[r][l] = z;
        }

    const int klane = (lane >> 4) * 8;
    const int lrow = lane & 15;

    for (int p = 0; p < 64; ++p) {
        const int cur = p & 1;
        // issue next-pair loads early (latency hides under MFMAs)
        uint32x4 nx0, nx1, nx2;
        if (p < 63) {
            const unsigned char* g = bpb + (size_t)(p + 1) * 24576;
            nx0 = *(const uint32x4*)(g + 0 * 8192 + soff);
            nx1 = *(const uint32x4*)(g + 1 * 8192 + soff);
            nx2 = *(const uint32x4*)(g + 2 * 8192 + soff);
        }

        const int s = 2 * p + kg;           // this wave's K-step (0..127)
        // A-frags from mask bits: bf16 0.0/1.0 built in-register
        short8 a[4];
#pragma unroll
        for (int r = 0; r < 4; ++r) {
            unsigned int w = maskw[(r * 16 + lrow) * 129 + s];
            unsigned int m8 = (w >> klane) & 0xFFu;
            unsigned int x = m8 | (m8 << 15);
            uint32x4 u;
#pragma unroll
            for (int t = 0; t < 4; ++t)
                u[t] = ((x >> (2 * t)) & 0x10001u) * 0x3F80u;
            a[r] = __builtin_bit_cast(short8, u);
        }
        // B-frags (3 digit planes) from LDS
        const unsigned char* bb = lds + cur * 24576 + (kg * 12 + cg * 3) * 1024 + lane * 16;
        short8 bf0 = *(const short8*)(bb);
        short8 bf1 = *(const short8*)(bb + 1024);
        short8 bf2 = *(const short8*)(bb + 2048);
#pragma unroll
        for (int r = 0; r < 4; ++r) {
            acc[r][0] = __builtin_amdgcn_mfma_f32_16x16x32_bf16(a[r], bf0, acc[r][0], 0, 0, 0);
            acc[r][1] = __builtin_amdgcn_mfma_f32_16x16x32_bf16(a[r], bf1, acc[r][1], 0, 0, 0);
            acc[r][2] = __builtin_amdgcn_mfma_f32_16x16x32_bf16(a[r], bf2, acc[r][2], 0, 0, 0);
        }
        // write staged regs -> other buffer
        if (p < 63) {
            unsigned char* l = lds + (cur ^ 1) * 24576;
            *(uint32x4*)(l + 0 * 8192 + soff) = nx0;
            *(uint32x4*)(l + 1 * 8192 + soff) = nx1;
            *(uint32x4*)(l + 2 * 8192 + soff) = nx2;
        }
        __syncthreads();
    }

    // merge kg=1 partials into kg=0 via LDS
    if (kg == 1) {
        unsigned char* dst = lds + cg * 12288 + lane * 192;
#pragma unroll
        for (int r = 0; r < 4; ++r)
#pragma unroll
            for (int l = 0; l < 3; ++l)
                *(f32x4*)(dst + (r * 3 + l) * 16) = acc[r][l];
    }
    __syncthreads();
    if (kg == 0) {
        const unsigned char* src2 = lds + cg * 12288 + lane * 192;
#pragma unroll
        for (int r = 0; r < 4; ++r)
#pragma unroll
            for (int l = 0; l < 3; ++l)
                acc[r][l] += *(const f32x4*)(src2 + (r * 3 + l) * 16);

        const int o = cg * 16 + lrow;
#pragma unroll
        for (int r = 0; r < 4; ++r) {
#pragma unroll
            for (int jj = 0; jj < 4; ++jj) {
                double S = (double)acc[r][0][jj] + 256.0 * (double)acc[r][1][jj]
                         + 65536.0 * (double)acc[r][2][jj];   // exact integer
                int i = i0 + r * 16 + (lane >> 4) * 4 + jj;   // C/D row mapping (m89)
                size_t oi = ((size_t)b * GN + i) * FOUT + o;
                out[oi] = S < 0.0 ? 1.0f : 0.0f;
                if (fabs(S) <= 2048.0) {                       // borderline: exact recompute
                    unsigned int idx = atomicAdd(counter, 1u);
                    if (idx < FLAG_CAP) flags[idx] = (unsigned int)oi;
                }
            }
        }
    }
}

// ---- kernel 4: exact f64 recompute for flagged (borderline) outputs ----
__global__ __launch_bounds__(256) void fixup_kernel(const double* __restrict__ hW,
                                                    const unsigned int* __restrict__ mbits,
                                                    const unsigned int* __restrict__ counter,
                                                    const unsigned int* __restrict__ flags,
                                                    float* __restrict__ out) {
    unsigned int cnt = *counter;
    if (cnt > FLAG_CAP) cnt = FLAG_CAP;
    int g = blockIdx.x * 4 + (threadIdx.x >> 6);
    int lane = threadIdx.x & 63;
    for (unsigned int f = g; f < cnt; f += 256) {
        unsigned int e = flags[f];
        int o = e & 63;
        int i = (e >> 6) & 4095;
        int b = (int)(e >> 18);
        double s = 0.0;
        for (int t = 0; t < 64; ++t) {
            int j = t * 64 + lane;
            unsigned int w = mbits[(size_t)i * 128 + (j >> 5)];
            if ((w >> (j & 31)) & 1u)
                s += hW[((size_t)b * GN + j) * FOUT + o];
        }
        for (int d = 32; d >= 1; d >>= 1) s += __shfl_down(s, d, 64);
        if (lane == 0) out[e] = s < 0.0 ? 1.0f : 0.0f;
    }
}

extern "C" void kernel_launch(void* const* d_in, const int* in_sizes, int n_in,
                              void* d_out, int out_size, void* d_ws, size_t ws_size,
                              hipStream_t stream) {
    const float* h   = (const float*)d_in[0];   // [4,4096,128]
    const int*   adj = (const int*)d_in[1];     // [4096,4096]
    const float* W   = (const float*)d_in[2];   // [128,64]
    float* out = (float*)d_out;                 // [4,4096,64]

    char* ws = (char*)d_ws;
    double* hW           = (double*)ws;                                   // 8 MB
    unsigned short* Bp   = (unsigned short*)(ws + 8388608);               // 6.29 MB
    unsigned int* mbits  = (unsigned int*)(ws + 8388608 + 6291456);       // 2 MB
    unsigned int* counter= (unsigned int*)(ws + 16777216);
    unsigned int* flags  = (unsigned int*)(ws + 16777216 + 256);          // 1 MB

    pack_kernel<<<(GN * (GN / 64)) / 4, 256, 0, stream>>>(adj, mbits);
    hw_kernel<<<GB * GN, 64, 0, stream>>>(h, W, hW, Bp);
    hipMemsetAsync(counter, 0, 4, stream);
    gemm_kernel<<<256, 512, 0, stream>>>((const unsigned char*)Bp, mbits, out, flags, counter);
    fixup_kernel<<<64, 256, 0, stream>>>(hW, mbits, counter, flags, out);
}

// Round 3
// 90.524 us; speedup vs baseline: 7.8060x; 1.3971x over previous
//
#include <hip/hip_runtime.h>
#include <hip/hip_bf16.h>

// GraphAttentionLayer collapse: out[b,i,o] = (S_mask[b,i,o] < 0) ? 1 : 0,
// S_mask = sum_{adj[i,j]==0} hW[b,j,o]  (|9e15*S_mask| >> |softmax part| => sigmoid saturates).
// Exact i8 MFMA path:
//   q = rint(hW*2^16) = d0 + 256*d1 + 65536*d2, balanced digits in [-128,127] (exact i8).
//   mask bit 0/1 exact i8. mfma_i32 accumulation is integer-exact.
//   S = c0 + 256*c1 + 65536*c2 (f64, exact). |S| > 2048 => sign reliable (rint err <= 0.5 * 4096).
//   else: flagged output recomputed exactly in f64 by fixup kernel (reads adj directly).

#define GN 4096
#define GB 4
#define FIN 128
#define FOUT 64
#define FLAG_CAP 65536

typedef int i32x4 __attribute__((ext_vector_type(4)));
typedef unsigned int uint32x4 __attribute__((ext_vector_type(4)));
typedef float f32x4 __attribute__((ext_vector_type(4)));

// ---- kernel 1: adj -> transposed bitmask tmask[rt][s][lane] (u64) ----
// bit (r*16 + jj) of tmask[rt][s][l] = (adj[rt*64 + r*16 + (l&15)][s*64 + (l>>4)*16 + jj] == 0)
__global__ __launch_bounds__(256) void pack_kernel(const int* __restrict__ adj,
                                                   unsigned long long* __restrict__ tmask) {
    int wid = blockIdx.x * 4 + (threadIdx.x >> 6);
    int lane = threadIdx.x & 63;
    int rt = wid >> 6, s = wid & 63;
    int row16 = lane & 15, g = lane >> 4;
    const int* base = adj + ((size_t)(rt * 64 + row16) * GN) + s * 64 + g * 16;
    unsigned long long res = 0ull;
#pragma unroll
    for (int r = 0; r < 4; ++r) {
        const i32x4* p = (const i32x4*)(base + (size_t)r * 16 * GN);
        unsigned int b16 = 0;
#pragma unroll
        for (int q = 0; q < 4; ++q) {
            i32x4 v = p[q];
            b16 |= (v.x == 0 ? 1u : 0u) << (q * 4);
            b16 |= (v.y == 0 ? 2u : 0u) << (q * 4);
            b16 |= (v.z == 0 ? 4u : 0u) << (q * 4);
            b16 |= (v.w == 0 ? 8u : 0u) << (q * 4);
        }
        res |= (unsigned long long)b16 << (r * 16);
    }
    tmask[(size_t)wid * 64 + lane] = res;
}

// ---- kernel 2: hW = h @ W in f64 + packed digits Dq (coalesced u32 stores) ----
__global__ __launch_bounds__(256) void hw_kernel(const float* __restrict__ h,
                                                 const float* __restrict__ W,
                                                 double* __restrict__ hW,
                                                 unsigned int* __restrict__ Dq) {
    const int grp = threadIdx.x >> 6;
    const int o = threadIdx.x & 63;
    const int bn = blockIdx.x * 4 + grp;
    __shared__ float hs[4][FIN];
    {
        const f32x4* src = (const f32x4*)(h + (size_t)blockIdx.x * 4 * FIN);
        f32x4* dst = (f32x4*)&hs[0][0];
        if (threadIdx.x < 128) dst[threadIdx.x] = src[threadIdx.x];
    }
    __syncthreads();
    double a0 = 0, a1 = 0, a2 = 0, a3 = 0;
#pragma unroll
    for (int i = 0; i < FIN; i += 4) {
        a0 = fma((double)hs[grp][i],     (double)W[i * FOUT + o],       a0);
        a1 = fma((double)hs[grp][i + 1], (double)W[(i + 1) * FOUT + o], a1);
        a2 = fma((double)hs[grp][i + 2], (double)W[(i + 2) * FOUT + o], a2);
        a3 = fma((double)hs[grp][i + 3], (double)W[(i + 3) * FOUT + o], a3);
    }
    double acc = (a0 + a1) + (a2 + a3);
    hW[(size_t)bn * FOUT + o] = acc;

    int qi = (int)llrint(acc * 65536.0);
    int d0 = ((qi + 128) & 255) - 128; qi = (qi - d0) >> 8;
    int d1 = ((qi + 128) & 255) - 128; qi = (qi - d1) >> 8;  // qi now = d2
    unsigned int packed = (unsigned int)(d0 & 255) | ((unsigned int)(d1 & 255) << 8)
                        | ((unsigned int)(qi & 255) << 16);
    Dq[(size_t)bn * FOUT + o] = packed;
}

// ---- kernel 3: Dq -> Bp i8 planes in MFMA-fragment-linear order (all coalesced) ----
// Bp[b][p][pl*4096 + cg*1024 + g*256 + col16*16 + jj], element (j=p*64+g*16+jj, o=cg*16+col16)
__global__ __launch_bounds__(256) void repack_kernel(const unsigned int* __restrict__ Dq,
                                                     unsigned char* __restrict__ Bp) {
    const int b = blockIdx.x >> 6, p = blockIdx.x & 63;
    const int t = threadIdx.x;
    const int cg = t >> 6, g = (t >> 4) & 3, col16 = t & 15;
    const int o = cg * 16 + col16;
    const unsigned int* src = Dq + ((size_t)b * GN + p * 64 + g * 16) * FOUT + o;
    uint32x4 w0 = {0, 0, 0, 0}, w1 = {0, 0, 0, 0}, w2 = {0, 0, 0, 0};
#pragma unroll
    for (int jj = 0; jj < 16; ++jj) {
        unsigned int d = src[(size_t)jj * FOUT];
        int wi = jj >> 2, sh = (jj & 3) * 8;
        w0[wi] |= ((d) & 255u) << sh;
        w1[wi] |= ((d >> 8) & 255u) << sh;
        w2[wi] |= ((d >> 16) & 255u) << sh;
    }
    unsigned char* dst = Bp + (size_t)blockIdx.x * 12288 + (size_t)cg * 1024 + g * 256 + col16 * 16;
    *(uint32x4*)(dst) = w0;
    *(uint32x4*)(dst + 4096) = w1;
    *(uint32x4*)(dst + 8192) = w2;
}

// ---- kernel 4: exact i8-MFMA masked-sum GEMM + sign epilogue ----
__global__ __launch_bounds__(512, 2) void gemm_kernel(const unsigned char* __restrict__ Bp,
                                                      const unsigned long long* __restrict__ tmask,
                                                      float* __restrict__ out,
                                                      unsigned int* __restrict__ flags,
                                                      unsigned int* __restrict__ counter) {
    __shared__ __align__(16) unsigned char lds[49152];
    const int tid = threadIdx.x, lane = tid & 63, wv = tid >> 6;
    const int cg = wv & 3, kg = wv >> 2;          // 4 col-groups x 2 K-parities
    const int rt = (int)blockIdx.x >> 2, b = (int)blockIdx.x & 3;

    const unsigned char* bpb = Bp + (size_t)b * (64 * 12288);
    const unsigned long long* tm = tmask + (size_t)rt * 4096;   // [s][lane]

    // prologue: stage chunk-pair 0 (24 KB) into buf0 via global_load_lds width=16
#pragma unroll
    for (int is = 0; is < 3; ++is)
        __builtin_amdgcn_global_load_lds((const unsigned int*)(bpb + is * 8192 + tid * 16),
                                         (unsigned int*)(lds + is * 8192 + tid * 16), 16, 0, 0);
    unsigned long long mcur = tm[(size_t)kg * 64 + lane];
    __syncthreads();   // drains vmcnt(0): staged B + mcur ready

    i32x4 acc[4][3];
#pragma unroll
    for (int r = 0; r < 4; ++r)
#pragma unroll
        for (int pl = 0; pl < 3; ++pl) {
            i32x4 z = {0, 0, 0, 0};
            acc[r][pl] = z;
        }

    for (int t = 0; t < 32; ++t) {
        const int cur = t & 1;
        if (t < 31) {
#pragma unroll
            for (int is = 0; is < 3; ++is)
                __builtin_amdgcn_global_load_lds(
                    (const unsigned int*)(bpb + (size_t)(t + 1) * 24576 + is * 8192 + tid * 16),
                    (unsigned int*)(lds + (cur ^ 1) * 24576 + is * 8192 + tid * 16), 16, 0, 0);
        }
        unsigned long long mnext = 0ull;
        if (t < 31) mnext = tm[(size_t)((t + 1) * 2 + kg) * 64 + lane];

        // A-frags (16 i8 0/1 per lane) from mask bits: nibble -> byte spread
        const unsigned int mlo = (unsigned int)mcur, mhi = (unsigned int)(mcur >> 32);
        i32x4 afr[4];
#pragma unroll
        for (int r = 0; r < 4; ++r) {
            unsigned int half = (r >> 1) ? mhi : mlo;
            unsigned int w16 = (r & 1) ? (half >> 16) : (half & 0xFFFFu);
            uint32x4 u;
#pragma unroll
            for (int q = 0; q < 4; ++q)
                u[q] = (((w16 >> (4 * q)) & 0xFu) * 0x00204081u) & 0x01010101u;
            afr[r] = __builtin_bit_cast(i32x4, u);
        }
        // B-frags: 3 digit planes, lane-linear LDS reads
        const unsigned char* bb = lds + cur * 24576 + kg * 12288 + cg * 1024 + lane * 16;
        i32x4 b0 = *(const i32x4*)(bb);
        i32x4 b1 = *(const i32x4*)(bb + 4096);
        i32x4 b2 = *(const i32x4*)(bb + 8192);
#pragma unroll
        for (int r = 0; r < 4; ++r) {
            acc[r][0] = __builtin_amdgcn_mfma_i32_16x16x64_i8(afr[r], b0, acc[r][0], 0, 0, 0);
            acc[r][1] = __builtin_amdgcn_mfma_i32_16x16x64_i8(afr[r], b1, acc[r][1], 0, 0, 0);
            acc[r][2] = __builtin_amdgcn_mfma_i32_16x16x64_i8(afr[r], b2, acc[r][2], 0, 0, 0);
        }
        __syncthreads();
        mcur = mnext;
    }

    // merge kg=1 partials into kg=0 via LDS (reuse staging buffer: 4*64*192 = 49152 B)
    if (kg == 1) {
        unsigned char* dst = lds + cg * 12288 + lane * 192;
#pragma unroll
        for (int r = 0; r < 4; ++r)
#pragma unroll
            for (int pl = 0; pl < 3; ++pl)
                *(i32x4*)(dst + (r * 3 + pl) * 16) = acc[r][pl];
    }
    __syncthreads();
    if (kg == 0) {
        const unsigned char* s2 = lds + cg * 12288 + lane * 192;
#pragma unroll
        for (int r = 0; r < 4; ++r)
#pragma unroll
            for (int pl = 0; pl < 3; ++pl) {
                i32x4 v = *(const i32x4*)(s2 + (r * 3 + pl) * 16);
#pragma unroll
                for (int q = 0; q < 4; ++q) acc[r][pl][q] += v[q];
            }

        const int o = cg * 16 + (lane & 15);
#pragma unroll
        for (int r = 0; r < 4; ++r) {
#pragma unroll
            for (int q = 0; q < 4; ++q) {
                double S = (double)acc[r][0][q] + 256.0 * (double)acc[r][1][q]
                         + 65536.0 * (double)acc[r][2][q];     // exact integer
                int i = rt * 64 + r * 16 + (lane >> 4) * 4 + q;  // C/D row map (m89)
                size_t oi = ((size_t)b * GN + i) * FOUT + o;
                out[oi] = S < 0.0 ? 1.0f : 0.0f;
                if (fabs(S) <= 2048.0) {
                    unsigned int idx = atomicAdd(counter, 1u);
                    if (idx < FLAG_CAP) flags[idx] = (unsigned int)oi;
                }
            }
        }
    }
}

// ---- kernel 5: exact f64 recompute for borderline outputs (reads adj directly) ----
__global__ __launch_bounds__(256) void fixup_kernel(const int* __restrict__ adj,
                                                    const double* __restrict__ hW,
                                                    const unsigned int* __restrict__ counter,
                                                    const unsigned int* __restrict__ flags,
                                                    float* __restrict__ out) {
    unsigned int cnt = *counter;
    if (cnt > FLAG_CAP) cnt = FLAG_CAP;
    int wid = blockIdx.x * 4 + (threadIdx.x >> 6);
    int lane = threadIdx.x & 63;
    for (unsigned int f = wid; f < cnt; f += 256) {
        unsigned int e = flags[f];
        int o = e & 63;
        int i = (e >> 6) & 4095;
        int b = (int)(e >> 18);
        double s = 0.0;
        for (int it = 0; it < 64; ++it) {
            int j = it * 64 + lane;
            int av = adj[(size_t)i * GN + j];
            double v = hW[((size_t)b * GN + j) * FOUT + o];
            s += (av == 0) ? v : 0.0;
        }
#pragma unroll
        for (int d = 32; d >= 1; d >>= 1) s += __shfl_down(s, d, 64);
        if (lane == 0) out[e] = s < 0.0 ? 1.0f : 0.0f;
    }
}

extern "C" void kernel_launch(void* const* d_in, const int* in_sizes, int n_in,
                              void* d_out, int out_size, void* d_ws, size_t ws_size,
                              hipStream_t stream) {
    const float* h   = (const float*)d_in[0];   // [4,4096,128]
    const int*   adj = (const int*)d_in[1];     // [4096,4096]
    const float* W   = (const float*)d_in[2];   // [128,64]
    float* out = (float*)d_out;                 // [4,4096,64] f32

    char* ws = (char*)d_ws;
    double* hW              = (double*)ws;                              // 8 MB
    unsigned int* Dq        = (unsigned int*)(ws + 8388608);            // 4 MB (dead after repack)
    unsigned char* Bp       = (unsigned char*)(ws + 12582912);          // 3 MB
    unsigned long long* tmask = (unsigned long long*)(ws + 15728640);   // 2 MB
    unsigned int* counter   = (unsigned int*)(ws + 8388608);            // overlaps dead Dq
    unsigned int* flags     = (unsigned int*)(ws + 8388608 + 256);      // 256 KB

    pack_kernel<<<1024, 256, 0, stream>>>(adj, tmask);
    hw_kernel<<<4096, 256, 0, stream>>>(h, W, hW, Dq);
    repack_kernel<<<256, 256, 0, stream>>>(Dq, Bp);
    hipMemsetAsync(counter, 0, 4, stream);
    gemm_kernel<<<256, 512, 0, stream>>>(Bp, tmask, out, flags, counter);
    fixup_kernel<<<64, 256, 0, stream>>>(adj, hW, counter, flags, out);
}

// Round 5
// 90.005 us; speedup vs baseline: 7.8510x; 1.0058x over previous
//
#include <hip/hip_runtime.h>
#include <hip/hip_bf16.h>

// GraphAttentionLayer collapse: out[b,i,o] = (S_mask[b,i,o] < 0) ? 1 : 0,
// S_mask = sum_{adj[i,j]==0} hW[b,j,o]  (|9e15*S_mask| >> |softmax term| => sigmoid saturates).
// Exact i8 MFMA path:
//   q = rint(hW*2^16) = d0 + 256*d1 + 65536*d2, balanced digits in [-128,127] (exact i8;
//   covers |hW| <= 128, observed max ~60). mask bit 0/1 exact i8. i32 MFMA accumulation exact.
//   S = c0 + 256*c1 + 65536*c2 (f64, exact integers). |S| > 2048 => sign reliable
//   (worst-case rint error 0.5*4096). else: exact f64 recompute in fixup kernel.
//
// ROUND-4 BUG FIX: hw_kernel needs 4096 blocks (4 rows/block, 16384 rows); round 4
// launched 1024 -> hW for batches 1..3 never computed -> wrong signs. Grid restored.

#define GN 4096
#define GB 4
#define FIN 128
#define FOUT 64
#define FLAG_CAP 65536

typedef int i32x4 __attribute__((ext_vector_type(4)));
typedef unsigned int uint32x4 __attribute__((ext_vector_type(4)));
typedef float f32x4 __attribute__((ext_vector_type(4)));

// ---- kernel 1: adj -> A-operand 0/1 bytes in MFMA-fragment-linear order ----
// Aexp[(rt*64+s)*4096 + r*1024 + lane*16 + jj] = (adj[rt*64+r*16+(lane&15)][s*64+(lane>>4)*16+jj]==0)
__global__ __launch_bounds__(256) void pack_kernel(const int* __restrict__ adj,
                                                   unsigned char* __restrict__ Aexp,
                                                   unsigned int* __restrict__ counter) {
    if (blockIdx.x == 0 && threadIdx.x == 0) *counter = 0;   // replaces 40us hipMemsetAsync
    int wid = blockIdx.x * 4 + (threadIdx.x >> 6);
    int lane = threadIdx.x & 63;
    int rt = wid >> 6, s = wid & 63;
    int row16 = lane & 15, g = lane >> 4;
    const int* base = adj + (size_t)(rt * 64 + row16) * GN + s * 64 + g * 16;
    unsigned char* dst = Aexp + (size_t)wid * 4096 + lane * 16;
#pragma unroll
    for (int r = 0; r < 4; ++r) {
        const i32x4* p = (const i32x4*)(base + (size_t)r * 16 * GN);
        unsigned int b16 = 0;
#pragma unroll
        for (int q = 0; q < 4; ++q) {
            i32x4 v = p[q];
            b16 |= (v.x == 0 ? 1u : 0u) << (q * 4);
            b16 |= (v.y == 0 ? 2u : 0u) << (q * 4);
            b16 |= (v.z == 0 ? 4u : 0u) << (q * 4);
            b16 |= (v.w == 0 ? 8u : 0u) << (q * 4);
        }
        uint32x4 u;
#pragma unroll
        for (int q = 0; q < 4; ++q)
            u[q] = (((b16 >> (4 * q)) & 0xFu) * 0x00204081u) & 0x01010101u;
        *(uint32x4*)(dst + r * 1024) = u;   // lane-linear 16B store, fully coalesced
    }
}

// ---- kernel 2: hW = h @ W in f64 ----
__global__ __launch_bounds__(256) void hw_kernel(const float* __restrict__ h,
                                                 const float* __restrict__ W,
                                                 double* __restrict__ hW) {
    const int grp = threadIdx.x >> 6;
    const int o = threadIdx.x & 63;
    const int bn = blockIdx.x * 4 + grp;
    __shared__ float hs[4][FIN];
    {
        const f32x4* src = (const f32x4*)(h + (size_t)blockIdx.x * 4 * FIN);
        f32x4* dst = (f32x4*)&hs[0][0];
        if (threadIdx.x < 128) dst[threadIdx.x] = src[threadIdx.x];
    }
    __syncthreads();
    double a0 = 0, a1 = 0, a2 = 0, a3 = 0;
#pragma unroll
    for (int i = 0; i < FIN; i += 4) {
        a0 = fma((double)hs[grp][i],     (double)W[i * FOUT + o],       a0);
        a1 = fma((double)hs[grp][i + 1], (double)W[(i + 1) * FOUT + o], a1);
        a2 = fma((double)hs[grp][i + 2], (double)W[(i + 2) * FOUT + o], a2);
        a3 = fma((double)hs[grp][i + 3], (double)W[(i + 3) * FOUT + o], a3);
    }
    double acc = (a0 + a1) + (a2 + a3);
    hW[(size_t)bn * FOUT + o] = acc;
}

// ---- kernel 3: hW -> Bp i8 digit planes in MFMA-fragment-linear order ----
// Bp[b][p][pl*4096 + cg*1024 + g*256 + col16*16 + jj], element (j=p*64+g*16+jj, o=cg*16+col16)
__global__ __launch_bounds__(256) void repack_kernel(const double* __restrict__ hW,
                                                     unsigned char* __restrict__ Bp) {
    const int b = blockIdx.x >> 6, p = blockIdx.x & 63;
    const int t = threadIdx.x;
    const int cg = t >> 6, g = (t >> 4) & 3, col16 = t & 15;
    const int o = cg * 16 + col16;
    const double* src = hW + ((size_t)b * GN + p * 64 + g * 16) * FOUT + o;
    uint32x4 w0 = {0, 0, 0, 0}, w1 = {0, 0, 0, 0}, w2 = {0, 0, 0, 0};
#pragma unroll
    for (int jj = 0; jj < 16; ++jj) {
        double v = src[(size_t)jj * FOUT];
        int qi = (int)llrint(v * 65536.0);
        int d0 = ((qi + 128) & 255) - 128; qi = (qi - d0) >> 8;
        int d1 = ((qi + 128) & 255) - 128; qi = (qi - d1) >> 8;  // qi now = d2
        int wi = jj >> 2, sh = (jj & 3) * 8;
        w0[wi] |= (unsigned int)(d0 & 255) << sh;
        w1[wi] |= (unsigned int)(d1 & 255) << sh;
        w2[wi] |= (unsigned int)(qi & 255) << sh;
    }
    unsigned char* dst = Bp + (size_t)blockIdx.x * 12288 + (size_t)cg * 1024 + g * 256 + col16 * 16;
    *(uint32x4*)(dst) = w0;
    *(uint32x4*)(dst + 4096) = w1;
    *(uint32x4*)(dst + 8192) = w2;
}

// ---- kernel 4: exact i8-MFMA masked-sum GEMM + sign epilogue ----
__global__ __launch_bounds__(512, 1) void gemm_kernel(const unsigned char* __restrict__ Bp,
                                                      const unsigned char* __restrict__ Aexp,
                                                      float* __restrict__ out,
                                                      unsigned int* __restrict__ flags,
                                                      unsigned int* __restrict__ counter) {
    __shared__ __align__(16) unsigned char lds[65536];   // 2 x (A 8KB | B 24KB)
    const int tid = threadIdx.x, lane = tid & 63, wv = tid >> 6;
    const int cg = wv & 3, kg = wv >> 2;          // 4 col-groups x 2 K-parities
    const int rt = (int)blockIdx.x >> 2, b = (int)blockIdx.x & 3;

    const unsigned char* bpb = Bp + (size_t)b * (64 * 12288);
    const unsigned char* apb = Aexp + (size_t)rt * (64 * 4096);

    // prologue: stage t=0 (A chunk-pair 8KB + B chunk-pair 24KB) into buf0
    __builtin_amdgcn_global_load_lds((const unsigned int*)(apb + tid * 16),
                                     (unsigned int*)(lds + tid * 16), 16, 0, 0);
#pragma unroll
    for (int seg = 0; seg < 3; ++seg)
        __builtin_amdgcn_global_load_lds((const unsigned int*)(bpb + seg * 8192 + tid * 16),
                                         (unsigned int*)(lds + 8192 + seg * 8192 + tid * 16), 16, 0, 0);
    __syncthreads();

    i32x4 acc[4][3];
#pragma unroll
    for (int r = 0; r < 4; ++r)
#pragma unroll
        for (int pl = 0; pl < 3; ++pl) {
            i32x4 z = {0, 0, 0, 0};
            acc[r][pl] = z;
        }

    const int aoff = kg * 4096 + lane * 16;
    const int boff = 8192 + kg * 12288 + cg * 1024 + lane * 16;

    for (int t = 0; t < 32; ++t) {
        const int cur = t & 1;
        const unsigned char* buf = lds + cur * 32768;
        unsigned char* nxt = lds + (cur ^ 1) * 32768;
        if (t < 31) {
            __builtin_amdgcn_global_load_lds((const unsigned int*)(apb + (size_t)(t + 1) * 8192 + tid * 16),
                                             (unsigned int*)(nxt + tid * 16), 16, 0, 0);
#pragma unroll
            for (int seg = 0; seg < 3; ++seg)
                __builtin_amdgcn_global_load_lds(
                    (const unsigned int*)(bpb + (size_t)(t + 1) * 24576 + seg * 8192 + tid * 16),
                    (unsigned int*)(nxt + 8192 + seg * 8192 + tid * 16), 16, 0, 0);
        }
        // A-frags: 0/1 bytes, lane-linear LDS reads (wave kg handles k-chunk s = 2t+kg)
        i32x4 afr[4];
#pragma unroll
        for (int r = 0; r < 4; ++r)
            afr[r] = *(const i32x4*)(buf + aoff + r * 1024);
        // B-frags: 3 digit planes
        i32x4 b0 = *(const i32x4*)(buf + boff);
        i32x4 b1 = *(const i32x4*)(buf + boff + 4096);
        i32x4 b2 = *(const i32x4*)(buf + boff + 8192);
#pragma unroll
        for (int r = 0; r < 4; ++r) {
            acc[r][0] = __builtin_amdgcn_mfma_i32_16x16x64_i8(afr[r], b0, acc[r][0], 0, 0, 0);
            acc[r][1] = __builtin_amdgcn_mfma_i32_16x16x64_i8(afr[r], b1, acc[r][1], 0, 0, 0);
            acc[r][2] = __builtin_amdgcn_mfma_i32_16x16x64_i8(afr[r], b2, acc[r][2], 0, 0, 0);
        }
        __syncthreads();
    }

    // merge kg=1 partials into kg=0 via LDS (4*64*192 = 49152 B, fits)
    if (kg == 1) {
        unsigned char* dst = lds + cg * 12288 + lane * 192;
#pragma unroll
        for (int r = 0; r < 4; ++r)
#pragma unroll
            for (int pl = 0; pl < 3; ++pl)
                *(i32x4*)(dst + (r * 3 + pl) * 16) = acc[r][pl];
    }
    __syncthreads();
    if (kg == 0) {
        const unsigned char* s2 = lds + cg * 12288 + lane * 192;
#pragma unroll
        for (int r = 0; r < 4; ++r)
#pragma unroll
            for (int pl = 0; pl < 3; ++pl) {
                i32x4 v = *(const i32x4*)(s2 + (r * 3 + pl) * 16);
#pragma unroll
                for (int q = 0; q < 4; ++q) acc[r][pl][q] += v[q];
            }

        const int o = cg * 16 + (lane & 15);
#pragma unroll
        for (int r = 0; r < 4; ++r) {
#pragma unroll
            for (int q = 0; q < 4; ++q) {
                double S = (double)acc[r][0][q] + 256.0 * (double)acc[r][1][q]
                         + 65536.0 * (double)acc[r][2][q];     // exact integer
                int i = rt * 64 + r * 16 + (lane >> 4) * 4 + q;  // C/D row map (m89)
                size_t oi = ((size_t)b * GN + i) * FOUT + o;
                out[oi] = S < 0.0 ? 1.0f : 0.0f;
                if (fabs(S) <= 2048.0) {
                    unsigned int idx = atomicAdd(counter, 1u);
                    if (idx < FLAG_CAP) flags[idx] = (unsigned int)oi;
                }
            }
        }
    }
}

// ---- kernel 5: exact f64 recompute for borderline outputs (reads adj directly) ----
__global__ __launch_bounds__(256) void fixup_kernel(const int* __restrict__ adj,
                                                    const double* __restrict__ hW,
                                                    const unsigned int* __restrict__ counter,
                                                    const unsigned int* __restrict__ flags,
                                                    float* __restrict__ out) {
    unsigned int cnt = *counter;
    if (cnt > FLAG_CAP) cnt = FLAG_CAP;
    int wid = blockIdx.x * 4 + (threadIdx.x >> 6);
    int lane = threadIdx.x & 63;
    for (unsigned int f = wid; f < cnt; f += 256) {
        unsigned int e = flags[f];
        int o = e & 63;
        int i = (e >> 6) & 4095;
        int b = (int)(e >> 18);
        double s = 0.0;
        for (int it = 0; it < 64; ++it) {
            int j = it * 64 + lane;
            int av = adj[(size_t)i * GN + j];
            double v = hW[((size_t)b * GN + j) * FOUT + o];
            s += (av == 0) ? v : 0.0;
        }
#pragma unroll
        for (int d = 32; d >= 1; d >>= 1) s += __shfl_down(s, d, 64);
        if (lane == 0) out[e] = s < 0.0 ? 1.0f : 0.0f;
    }
}

extern "C" void kernel_launch(void* const* d_in, const int* in_sizes, int n_in,
                              void* d_out, int out_size, void* d_ws, size_t ws_size,
                              hipStream_t stream) {
    const float* h   = (const float*)d_in[0];   // [4,4096,128]
    const int*   adj = (const int*)d_in[1];     // [4096,4096]
    const float* W   = (const float*)d_in[2];   // [128,64]
    float* out = (float*)d_out;                 // [4,4096,64] f32

    char* ws = (char*)d_ws;
    double* hW            = (double*)ws;                          // 8 MB @ 0
    unsigned char* Bp     = (unsigned char*)(ws + 8388608);       // 3 MB @ 8M
    unsigned char* Aexp   = (unsigned char*)(ws + 16777216);      // 16 MB @ 16M
    unsigned int* counter = (unsigned int*)(ws + 34603008);       // @ 33M
    unsigned int* flags   = (unsigned int*)(ws + 34603264);       // 256 KB

    pack_kernel<<<1024, 256, 0, stream>>>(adj, Aexp, counter);
    hw_kernel<<<4096, 256, 0, stream>>>(h, W, hW);   // FIX: 4096 blocks (was 1024)
    repack_kernel<<<256, 256, 0, stream>>>(hW, Bp);
    gemm_kernel<<<256, 512, 0, stream>>>(Bp, Aexp, out, flags, counter);
    fixup_kernel<<<64, 256, 0, stream>>>(adj, hW, counter, flags, out);
}

// Round 6
// 67.409 us; speedup vs baseline: 10.4827x; 1.3352x over previous
//
#include <hip/hip_runtime.h>
#include <hip/hip_bf16.h>

// GraphAttentionLayer collapse: out[b,i,o] = (S_mask[b,i,o] < 0) ? 1 : 0,
// S_mask = sum_{adj[i,j]==0} hW[b,j,o]  (|9e15*S_mask| >> |softmax term| => sigmoid saturates).
// Exact i8 MFMA path:
//   q = rint(hW*2^16) = d0 + 256*d1 + 65536*d2, balanced digits in [-128,127] (exact i8).
//   mask bit 0/1 exact i8; i32 MFMA accumulation exact.
//   S = c0 + 256*c1 + 65536*c2 (f64, exact integers). |S| > 2048 => sign reliable;
//   else exact f64 recompute in fixup kernel (~50 outputs expected).
// Round-6 changes: gemm uses counted-vmcnt 4-deep pipeline (T4) + tmask-based A
// (in-register build); fixup parallelized per-block; pack emits 2MB tmask.

#define GN 4096
#define GB 4
#define FIN 128
#define FOUT 64
#define FLAG_CAP 65536

typedef int i32x4 __attribute__((ext_vector_type(4)));
typedef unsigned int uint32x4 __attribute__((ext_vector_type(4)));
typedef float f32x4 __attribute__((ext_vector_type(4)));

// ---- kernel 1: adj -> transposed bitmask tmask[(rt*64+s)*64 + lane] (u64) ----
// bit (r*16 + jj) of tmask[rt*64+s][l] = (adj[rt*64 + r*16 + (l&15)][s*64 + (l>>4)*16 + jj] == 0)
// (verified by round 2/3 passes)
__global__ __launch_bounds__(256) void pack_kernel(const int* __restrict__ adj,
                                                   unsigned long long* __restrict__ tmask,
                                                   unsigned int* __restrict__ counter) {
    if (blockIdx.x == 0 && threadIdx.x == 0) *counter = 0;
    int wid = blockIdx.x * 4 + (threadIdx.x >> 6);
    int lane = threadIdx.x & 63;
    int rt = wid >> 6, s = wid & 63;
    int row16 = lane & 15, g = lane >> 4;
    const int* base = adj + (size_t)(rt * 64 + row16) * GN + s * 64 + g * 16;
    unsigned long long res = 0ull;
#pragma unroll
    for (int r = 0; r < 4; ++r) {
        const i32x4* p = (const i32x4*)(base + (size_t)r * 16 * GN);
        unsigned int b16 = 0;
#pragma unroll
        for (int q = 0; q < 4; ++q) {
            i32x4 v = p[q];
            b16 |= (v.x == 0 ? 1u : 0u) << (q * 4);
            b16 |= (v.y == 0 ? 2u : 0u) << (q * 4);
            b16 |= (v.z == 0 ? 4u : 0u) << (q * 4);
            b16 |= (v.w == 0 ? 8u : 0u) << (q * 4);
        }
        res |= (unsigned long long)b16 << (r * 16);
    }
    tmask[(size_t)wid * 64 + lane] = res;
}

// ---- kernel 2: hW = h @ W in f64 ----
__global__ __launch_bounds__(256) void hw_kernel(const float* __restrict__ h,
                                                 const float* __restrict__ W,
                                                 double* __restrict__ hW) {
    const int grp = threadIdx.x >> 6;
    const int o = threadIdx.x & 63;
    const int bn = blockIdx.x * 4 + grp;     // NEEDS grid = 4096 (round-4 lesson)
    __shared__ float hs[4][FIN];
    {
        const f32x4* src = (const f32x4*)(h + (size_t)blockIdx.x * 4 * FIN);
        f32x4* dst = (f32x4*)&hs[0][0];
        if (threadIdx.x < 128) dst[threadIdx.x] = src[threadIdx.x];
    }
    __syncthreads();
    double a0 = 0, a1 = 0, a2 = 0, a3 = 0;
#pragma unroll
    for (int i = 0; i < FIN; i += 4) {
        a0 = fma((double)hs[grp][i],     (double)W[i * FOUT + o],       a0);
        a1 = fma((double)hs[grp][i + 1], (double)W[(i + 1) * FOUT + o], a1);
        a2 = fma((double)hs[grp][i + 2], (double)W[(i + 2) * FOUT + o], a2);
        a3 = fma((double)hs[grp][i + 3], (double)W[(i + 3) * FOUT + o], a3);
    }
    double acc = (a0 + a1) + (a2 + a3);
    hW[(size_t)bn * FOUT + o] = acc;
}

// ---- kernel 3: hW -> Bp i8 digit planes in MFMA-fragment-linear order ----
// Bp[b][p][pl*4096 + cg*1024 + g*256 + col16*16 + jj], element (j=p*64+g*16+jj, o=cg*16+col16)
__global__ __launch_bounds__(256) void repack_kernel(const double* __restrict__ hW,
                                                     unsigned char* __restrict__ Bp) {
    const int b = blockIdx.x >> 6, p = blockIdx.x & 63;
    const int t = threadIdx.x;
    const int cg = t >> 6, g = (t >> 4) & 3, col16 = t & 15;
    const int o = cg * 16 + col16;
    const double* src = hW + ((size_t)b * GN + p * 64 + g * 16) * FOUT + o;
    uint32x4 w0 = {0, 0, 0, 0}, w1 = {0, 0, 0, 0}, w2 = {0, 0, 0, 0};
#pragma unroll
    for (int jj = 0; jj < 16; ++jj) {
        double v = src[(size_t)jj * FOUT];
        int qi = (int)llrint(v * 65536.0);
        int d0 = ((qi + 128) & 255) - 128; qi = (qi - d0) >> 8;
        int d1 = ((qi + 128) & 255) - 128; qi = (qi - d1) >> 8;  // qi now = d2
        int wi = jj >> 2, sh = (jj & 3) * 8;
        w0[wi] |= (unsigned int)(d0 & 255) << sh;
        w1[wi] |= (unsigned int)(d1 & 255) << sh;
        w2[wi] |= (unsigned int)(qi & 255) << sh;
    }
    unsigned char* dst = Bp + (size_t)blockIdx.x * 12288 + (size_t)cg * 1024 + g * 256 + col16 * 16;
    *(uint32x4*)(dst) = w0;
    *(uint32x4*)(dst + 4096) = w1;
    *(uint32x4*)(dst + 8192) = w2;
}

// ---- kernel 4: exact i8-MFMA masked-sum GEMM, counted-vmcnt 4-deep pipeline ----
__global__ __launch_bounds__(512, 1) void gemm_kernel(const unsigned char* __restrict__ Bp,
                                                      const unsigned long long* __restrict__ tmask,
                                                      float* __restrict__ out,
                                                      unsigned int* __restrict__ flags,
                                                      unsigned int* __restrict__ counter) {
    // LDS: 4 x 24KB B ring buffers + 32KB tmask slice = 128KB
    __shared__ __align__(16) unsigned char lds[4 * 24576 + 32768];
    unsigned long long* tml = (unsigned long long*)(lds + 4 * 24576);

    const int tid = threadIdx.x, lane = tid & 63, wv = tid >> 6;
    const int cg = wv & 3, kg = wv >> 2;          // 4 col-groups x 2 K-parities
    const int rt = (int)blockIdx.x >> 2, b = (int)blockIdx.x & 3;

    const unsigned char* bpb = Bp + (size_t)b * (64 * 12288);
    const unsigned char* tmg = (const unsigned char*)(tmask + (size_t)rt * 4096);

    // one-time: stage tmask slice (32KB) + B steps 0..2 (3 x 24KB) into LDS
#pragma unroll
    for (int q = 0; q < 4; ++q)
        __builtin_amdgcn_global_load_lds((const unsigned int*)(tmg + q * 8192 + tid * 16),
                                         (unsigned int*)(lds + 4 * 24576 + q * 8192 + tid * 16), 16, 0, 0);
#pragma unroll
    for (int t0 = 0; t0 < 3; ++t0)
#pragma unroll
        for (int seg = 0; seg < 3; ++seg)
            __builtin_amdgcn_global_load_lds(
                (const unsigned int*)(bpb + (size_t)t0 * 24576 + seg * 8192 + tid * 16),
                (unsigned int*)(lds + t0 * 24576 + seg * 8192 + tid * 16), 16, 0, 0);
    __syncthreads();   // prologue drain (vmcnt0): bufs 0..2 + tmask resident

    i32x4 acc[4][3];
#pragma unroll
    for (int r = 0; r < 4; ++r)
#pragma unroll
        for (int pl = 0; pl < 3; ++pl) {
            i32x4 z = {0, 0, 0, 0};
            acc[r][pl] = z;
        }

    const int boff = cg * 1024 + lane * 16;   // within a 12KB kg-half

    // One step: wait own vmcnt to VM, barrier (=> buf[T&3] fully written by all
    // waves), ds_read B frags + tmask word, optionally issue T+3 into buf[(T+3)&3]
    // (safe: that buffer's last readers finished before this barrier), 12 MFMA.
#define GSTEP(T, VM, DO_ISSUE)                                                          \
    {                                                                                   \
        asm volatile("s_waitcnt vmcnt(" #VM ")" ::: "memory");                          \
        __builtin_amdgcn_s_barrier();                                                   \
        const unsigned char* buf = lds + ((T) & 3) * 24576 + kg * 12288;                \
        i32x4 b0 = *(const i32x4*)(buf + boff);                                         \
        i32x4 b1 = *(const i32x4*)(buf + boff + 4096);                                  \
        i32x4 b2 = *(const i32x4*)(buf + boff + 8192);                                  \
        unsigned long long mw = tml[(size_t)(2 * (T) + kg) * 64 + lane];                \
        if (DO_ISSUE) {                                                                 \
            const unsigned char* gsrc = bpb + (size_t)((T) + 3) * 24576;                \
            unsigned char* gdst = lds + (((T) + 3) & 3) * 24576;                        \
            _Pragma("unroll")                                                           \
            for (int seg = 0; seg < 3; ++seg)                                           \
                __builtin_amdgcn_global_load_lds(                                       \
                    (const unsigned int*)(gsrc + seg * 8192 + tid * 16),                \
                    (unsigned int*)(gdst + seg * 8192 + tid * 16), 16, 0, 0);           \
        }                                                                               \
        const unsigned int mlo = (unsigned int)mw, mhi = (unsigned int)(mw >> 32);      \
        i32x4 afr[4];                                                                   \
        _Pragma("unroll")                                                               \
        for (int r = 0; r < 4; ++r) {                                                   \
            unsigned int half = (r >> 1) ? mhi : mlo;                                   \
            unsigned int w16 = (r & 1) ? (half >> 16) : (half & 0xFFFFu);               \
            uint32x4 u;                                                                 \
            _Pragma("unroll")                                                           \
            for (int q = 0; q < 4; ++q)                                                 \
                u[q] = (((w16 >> (4 * q)) & 0xFu) * 0x00204081u) & 0x01010101u;         \
            afr[r] = __builtin_bit_cast(i32x4, u);                                      \
        }                                                                               \
        _Pragma("unroll")                                                               \
        for (int r = 0; r < 4; ++r) {                                                   \
            acc[r][0] = __builtin_amdgcn_mfma_i32_16x16x64_i8(afr[r], b0, acc[r][0], 0, 0, 0); \
            acc[r][1] = __builtin_amdgcn_mfma_i32_16x16x64_i8(afr[r], b1, acc[r][1], 0, 0, 0); \
            acc[r][2] = __builtin_amdgcn_mfma_i32_16x16x64_i8(afr[r], b2, acc[r][2], 0, 0, 0); \
        }                                                                               \
    }

    for (int t = 0; t < 29; ++t) GSTEP(t, 6, 1)   // steady state: 6 loads in flight
    GSTEP(29, 6, 0)
    GSTEP(30, 3, 0)
    GSTEP(31, 0, 0)
#undef GSTEP

    // merge kg=1 partials into kg=0 via LDS (49152 B, reuses dead ring buffers)
    __syncthreads();
    if (kg == 1) {
        unsigned char* dst = lds + cg * 12288 + lane * 192;
#pragma unroll
        for (int r = 0; r < 4; ++r)
#pragma unroll
            for (int pl = 0; pl < 3; ++pl)
                *(i32x4*)(dst + (r * 3 + pl) * 16) = acc[r][pl];
    }
    __syncthreads();
    if (kg == 0) {
        const unsigned char* s2 = lds + cg * 12288 + lane * 192;
#pragma unroll
        for (int r = 0; r < 4; ++r)
#pragma unroll
            for (int pl = 0; pl < 3; ++pl) {
                i32x4 v = *(const i32x4*)(s2 + (r * 3 + pl) * 16);
#pragma unroll
                for (int q = 0; q < 4; ++q) acc[r][pl][q] += v[q];
            }

        const int o = cg * 16 + (lane & 15);
#pragma unroll
        for (int r = 0; r < 4; ++r) {
#pragma unroll
            for (int q = 0; q < 4; ++q) {
                double S = (double)acc[r][0][q] + 256.0 * (double)acc[r][1][q]
                         + 65536.0 * (double)acc[r][2][q];     // exact integer
                int i = rt * 64 + r * 16 + (lane >> 4) * 4 + q;  // C/D row map (m89)
                size_t oi = ((size_t)b * GN + i) * FOUT + o;
                out[oi] = S < 0.0 ? 1.0f : 0.0f;
                if (fabs(S) <= 2048.0) {
                    unsigned int idx = atomicAdd(counter, 1u);
                    if (idx < FLAG_CAP) flags[idx] = (unsigned int)oi;
                }
            }
        }
    }
}

// ---- kernel 5: exact f64 recompute for borderline outputs, one block per item ----
__global__ __launch_bounds__(256) void fixup_kernel(const int* __restrict__ adj,
                                                    const double* __restrict__ hW,
                                                    const unsigned int* __restrict__ counter,
                                                    const unsigned int* __restrict__ flags,
                                                    float* __restrict__ out) {
    __shared__ double red[4];
    unsigned int cnt = *counter;
    if (cnt > FLAG_CAP) cnt = FLAG_CAP;
    for (unsigned int f = blockIdx.x; f < cnt; f += gridDim.x) {
        unsigned int e = flags[f];
        int o = e & 63;
        int i = (e >> 6) & 4095;
        int b = (int)(e >> 18);
        double s = 0.0;
#pragma unroll
        for (int it = 0; it < 16; ++it) {
            int j = it * 256 + threadIdx.x;
            int av = adj[(size_t)i * GN + j];
            double v = hW[((size_t)b * GN + j) * FOUT + o];
            s += (av == 0) ? v : 0.0;
        }
#pragma unroll
        for (int d = 32; d >= 1; d >>= 1) s += __shfl_down(s, d, 64);
        if ((threadIdx.x & 63) == 0) red[threadIdx.x >> 6] = s;
        __syncthreads();
        if (threadIdx.x == 0) {
            double tot = (red[0] + red[1]) + (red[2] + red[3]);
            out[e] = tot < 0.0 ? 1.0f : 0.0f;
        }
        __syncthreads();   // red[] reused next item
    }
}

extern "C" void kernel_launch(void* const* d_in, const int* in_sizes, int n_in,
                              void* d_out, int out_size, void* d_ws, size_t ws_size,
                              hipStream_t stream) {
    const float* h   = (const float*)d_in[0];   // [4,4096,128]
    const int*   adj = (const int*)d_in[1];     // [4096,4096]
    const float* W   = (const float*)d_in[2];   // [128,64]
    float* out = (float*)d_out;                 // [4,4096,64] f32

    char* ws = (char*)d_ws;
    double* hW                = (double*)ws;                          // 8 MB @ 0
    unsigned char* Bp         = (unsigned char*)(ws + 8388608);       // 3 MB @ 8M
    unsigned long long* tmask = (unsigned long long*)(ws + 12582912); // 2 MB @ 12M
    unsigned int* counter     = (unsigned int*)(ws + 16777216);       // @ 16M
    unsigned int* flags       = (unsigned int*)(ws + 16777472);       // 256 KB

    pack_kernel<<<1024, 256, 0, stream>>>(adj, tmask, counter);
    hw_kernel<<<4096, 256, 0, stream>>>(h, W, hW);          // 4096 blocks (round-4 lesson!)
    repack_kernel<<<256, 256, 0, stream>>>(hW, Bp);
    gemm_kernel<<<256, 512, 0, stream>>>(Bp, tmask, out, flags, counter);
    fixup_kernel<<<64, 256, 0, stream>>>(adj, hW, counter, flags, out);
}